// Round 1
// baseline (1876.980 us; speedup 1.0000x reference)
//
#include <hip/hip_runtime.h>
#include <math.h>

#define TPB 256

// ---------------------------------------------------------------------------
// NT GEMM: out = (A @ W^T + bias) * scale
// A: [8192][512] row-major, W: [512][512] row-major (torch Linear weight)
// qkv_layout==1: out indexed as [B=4][H=8][T=2048][64]  (b=m>>11, t=m&2047,
//                h=n>>6, d=n&63)
// qkv_layout==0: out[m][n] row-major [8192][512]
// ---------------------------------------------------------------------------
__global__ __launch_bounds__(TPB)
void gemm_nt_kernel(const float* __restrict__ A,
                    const float* __restrict__ W,
                    const float* __restrict__ bias,
                    float* __restrict__ out,
                    float scale, int qkv_layout)
{
    __shared__ float As[64][68];   // stride 68: 16B-aligned rows, f4 reads
    __shared__ float Bs[64][65];   // stride 65: scalar reads, 2-way max

    const int K  = 512;
    const int t  = threadIdx.x;
    const int m0 = blockIdx.x * 64;
    const int n0 = blockIdx.y * 64;
    const int tq = t >> 4;
    const int tk = t & 15;

    float acc[4][4];
    #pragma unroll
    for (int i = 0; i < 4; ++i)
        #pragma unroll
        for (int j = 0; j < 4; ++j) acc[i][j] = 0.f;

    for (int k0 = 0; k0 < K; k0 += 64) {
        __syncthreads();
        #pragma unroll
        for (int p = 0; p < 4; ++p) {
            int g  = t + TPB * p;
            int r  = g >> 4;
            int kk = (g & 15) << 2;
            float4 av = *reinterpret_cast<const float4*>(&A[(size_t)(m0 + r) * K + k0 + kk]);
            As[r][kk+0] = av.x; As[r][kk+1] = av.y; As[r][kk+2] = av.z; As[r][kk+3] = av.w;
            float4 bv = *reinterpret_cast<const float4*>(&W[(size_t)(n0 + r) * K + k0 + kk]);
            Bs[r][kk+0] = bv.x; Bs[r][kk+1] = bv.y; Bs[r][kk+2] = bv.z; Bs[r][kk+3] = bv.w;
        }
        __syncthreads();

        #pragma unroll
        for (int kk = 0; kk < 64; kk += 4) {
            float a_[4][4];
            #pragma unroll
            for (int i = 0; i < 4; ++i) {
                float4 v4 = *reinterpret_cast<const float4*>(&As[tq*4 + i][kk]);
                a_[i][0] = v4.x; a_[i][1] = v4.y; a_[i][2] = v4.z; a_[i][3] = v4.w;
            }
            #pragma unroll
            for (int c = 0; c < 4; ++c) {
                float b_[4];
                #pragma unroll
                for (int j = 0; j < 4; ++j) b_[j] = Bs[tk*4 + j][kk + c];
                #pragma unroll
                for (int i = 0; i < 4; ++i)
                    #pragma unroll
                    for (int j = 0; j < 4; ++j)
                        acc[i][j] = fmaf(a_[i][c], b_[j], acc[i][j]);
            }
        }
    }

    #pragma unroll
    for (int i = 0; i < 4; ++i) {
        int m = m0 + tq*4 + i;
        #pragma unroll
        for (int j = 0; j < 4; ++j) {
            int n = n0 + tk*4 + j;
            float v = (acc[i][j] + bias[n]) * scale;
            if (qkv_layout) {
                int b = m >> 11, tt = m & 2047, h = n >> 6, d = n & 63;
                out[((((size_t)b*8 + h)*2048 + tt) << 6) + d] = v;
            } else {
                out[(size_t)m * 512 + n] = v;
            }
        }
    }
}

// ---------------------------------------------------------------------------
// Flash-style attention with multiplicative Tonnetz mask.
// Q pre-scaled by 1/sqrt(64). Q/K/V in [B*H][2048][64].
// Output written as [B][T][C] with c = h*64 + d (ready for out-proj GEMM).
// grid: (T/64, B*H), block: 256 (thread t: row-group tq=t>>4, col tk=t&15)
// ---------------------------------------------------------------------------
__global__ __launch_bounds__(TPB)
void attn_kernel(const float* __restrict__ Qg,
                 const float* __restrict__ Kg,
                 const float* __restrict__ Vg,
                 float* __restrict__ outg)
{
    __shared__ float Qs[64][68];
    __shared__ float Ks[64][65];
    __shared__ float Vs[64][65];
    __shared__ float Ps[64][68];
    __shared__ float m_s[64], l_s[64], c_s[64];
    __shared__ float wlut[16];

    const int t  = threadIdx.x;
    const int bh = blockIdx.y;
    const int q0 = blockIdx.x * 64;
    const float* Qb = Qg + ((size_t)bh * 2048 + q0) * 64;
    const float* Kb = Kg + (size_t)bh * 2048 * 64;
    const float* Vb = Vg + (size_t)bh * 2048 * 64;

    if (t < 16) wlut[t] = (t <= 2) ? 1.0f : __expf(-(float)t);
    if (t < 64) { m_s[t] = -3.0e38f; l_s[t] = 0.f; c_s[t] = 0.f; }

    #pragma unroll
    for (int p = 0; p < 4; ++p) {
        int g  = t + TPB * p;
        int r  = g >> 4;
        int kk = (g & 15) << 2;
        float4 v4 = *reinterpret_cast<const float4*>(&Qb[(size_t)r * 64 + kk]);
        Qs[r][kk+0] = v4.x; Qs[r][kk+1] = v4.y; Qs[r][kk+2] = v4.z; Qs[r][kk+3] = v4.w;
    }

    const int tq = t >> 4;
    const int tk = t & 15;

    int qx[4], qy[4];
    #pragma unroll
    for (int i = 0; i < 4; ++i) {
        int qi = q0 + tq*4 + i;
        qx[i] = qi % 12;
        qy[i] = (qi / 12) % 12;
    }

    float o[4][4];
    #pragma unroll
    for (int i = 0; i < 4; ++i)
        #pragma unroll
        for (int j = 0; j < 4; ++j) o[i][j] = 0.f;

    for (int k0 = 0; k0 < 2048; k0 += 64) {
        __syncthreads();   // previous PV reads done (also covers Q staging/init)
        #pragma unroll
        for (int p = 0; p < 4; ++p) {
            int g  = t + TPB * p;
            int r  = g >> 4;
            int kk = (g & 15) << 2;
            float4 kv = *reinterpret_cast<const float4*>(&Kb[(size_t)(k0 + r) * 64 + kk]);
            Ks[r][kk+0] = kv.x; Ks[r][kk+1] = kv.y; Ks[r][kk+2] = kv.z; Ks[r][kk+3] = kv.w;
            float4 vv = *reinterpret_cast<const float4*>(&Vb[(size_t)(k0 + r) * 64 + kk]);
            Vs[r][kk+0] = vv.x; Vs[r][kk+1] = vv.y; Vs[r][kk+2] = vv.z; Vs[r][kk+3] = vv.w;
        }
        __syncthreads();

        // S = Q K^T (sum over dk), 4x4 per thread
        float s_[4][4];
        #pragma unroll
        for (int i = 0; i < 4; ++i)
            #pragma unroll
            for (int j = 0; j < 4; ++j) s_[i][j] = 0.f;

        #pragma unroll
        for (int kk = 0; kk < 64; kk += 4) {
            float a_[4][4];
            #pragma unroll
            for (int i = 0; i < 4; ++i) {
                float4 v4 = *reinterpret_cast<const float4*>(&Qs[tq*4 + i][kk]);
                a_[i][0] = v4.x; a_[i][1] = v4.y; a_[i][2] = v4.z; a_[i][3] = v4.w;
            }
            #pragma unroll
            for (int c = 0; c < 4; ++c) {
                float b_[4];
                #pragma unroll
                for (int j = 0; j < 4; ++j) b_[j] = Ks[tk*4 + j][kk + c];
                #pragma unroll
                for (int i = 0; i < 4; ++i)
                    #pragma unroll
                    for (int j = 0; j < 4; ++j)
                        s_[i][j] = fmaf(a_[i][c], b_[j], s_[i][j]);
            }
        }

        // multiplicative Tonnetz mask
        int kx[4], ky[4];
        #pragma unroll
        for (int j = 0; j < 4; ++j) {
            int kj = k0 + tk*4 + j;
            kx[j] = kj % 12;
            ky[j] = (kj / 12) % 12;
        }
        #pragma unroll
        for (int i = 0; i < 4; ++i)
            #pragma unroll
            for (int j = 0; j < 4; ++j) {
                int dx = qx[i] - kx[j]; dx = dx < 0 ? -dx : dx; dx = dx < 12 - dx ? dx : 12 - dx;
                int dy = qy[i] - ky[j]; dy = dy < 0 ? -dy : dy; dy = dy < 12 - dy ? dy : 12 - dy;
                s_[i][j] *= wlut[dx + dy];
            }

        // online softmax per q-row (16 lanes per row, lockstep within wave)
        #pragma unroll
        for (int i = 0; i < 4; ++i) {
            int row = tq*4 + i;
            float tmax = fmaxf(fmaxf(s_[i][0], s_[i][1]), fmaxf(s_[i][2], s_[i][3]));
            #pragma unroll
            for (int mm = 1; mm < 16; mm <<= 1)
                tmax = fmaxf(tmax, __shfl_xor(tmax, mm, 16));
            float mold = m_s[row];
            float mnew = fmaxf(mold, tmax);
            float p0 = __expf(s_[i][0] - mnew);
            float p1 = __expf(s_[i][1] - mnew);
            float p2 = __expf(s_[i][2] - mnew);
            float p3 = __expf(s_[i][3] - mnew);
            *reinterpret_cast<float4*>(&Ps[row][tk*4]) = make_float4(p0, p1, p2, p3);
            float psum = (p0 + p1) + (p2 + p3);
            #pragma unroll
            for (int mm = 1; mm < 16; mm <<= 1)
                psum += __shfl_xor(psum, mm, 16);
            if (tk == 0) {
                float cf = __expf(mold - mnew);
                m_s[row] = mnew;
                c_s[row] = cf;
                l_s[row] = l_s[row] * cf + psum;
            }
        }
        __syncthreads();

        // O = O * c + P @ V
        float crow[4];
        #pragma unroll
        for (int i = 0; i < 4; ++i) crow[i] = c_s[tq*4 + i];
        #pragma unroll
        for (int i = 0; i < 4; ++i)
            #pragma unroll
            for (int j = 0; j < 4; ++j) o[i][j] *= crow[i];

        #pragma unroll
        for (int kc = 0; kc < 64; kc += 4) {
            float p_[4][4];
            #pragma unroll
            for (int i = 0; i < 4; ++i) {
                float4 v4 = *reinterpret_cast<const float4*>(&Ps[tq*4 + i][kc]);
                p_[i][0] = v4.x; p_[i][1] = v4.y; p_[i][2] = v4.z; p_[i][3] = v4.w;
            }
            #pragma unroll
            for (int c = 0; c < 4; ++c) {
                float v_[4];
                #pragma unroll
                for (int j = 0; j < 4; ++j) v_[j] = Vs[kc + c][tk*4 + j];
                #pragma unroll
                for (int i = 0; i < 4; ++i)
                    #pragma unroll
                    for (int j = 0; j < 4; ++j)
                        o[i][j] = fmaf(p_[i][c], v_[j], o[i][j]);
            }
        }
    }

    // finalize: divide by l, write [B][T][C] with c = h*64 + d
    const int b = bh >> 3;
    const int h = bh & 7;
    #pragma unroll
    for (int i = 0; i < 4; ++i) {
        int row = tq*4 + i;
        float inv = 1.0f / l_s[row];
        float4 ov = make_float4(o[i][0]*inv, o[i][1]*inv, o[i][2]*inv, o[i][3]*inv);
        size_t off = ((size_t)b * 2048 + q0 + row) * 512 + h*64 + tk*4;
        *reinterpret_cast<float4*>(&outg[off]) = ov;
    }
}

// ---------------------------------------------------------------------------
extern "C" void kernel_launch(void* const* d_in, const int* in_sizes, int n_in,
                              void* d_out, int out_size, void* d_ws, size_t ws_size,
                              hipStream_t stream)
{
    (void)in_sizes; (void)n_in; (void)out_size; (void)ws_size;
    const float* x  = (const float*)d_in[0];
    const float* Wq = (const float*)d_in[1];
    const float* bq = (const float*)d_in[2];
    const float* Wk = (const float*)d_in[3];
    const float* bk = (const float*)d_in[4];
    const float* Wv = (const float*)d_in[5];
    const float* bv = (const float*)d_in[6];
    const float* Wo = (const float*)d_in[7];
    const float* bo = (const float*)d_in[8];
    float* out = (float*)d_out;

    float* ws   = (float*)d_ws;
    const size_t SZ = (size_t)4 * 8 * 2048 * 64;   // 4,194,304 floats
    float* q_ws = ws;
    float* k_ws = ws + SZ;
    float* v_ws = ws + 2 * SZ;
    float* a_ws = ws + 3 * SZ;

    dim3 gg(128, 8);
    // Q scaled by 1/sqrt(dk)=0.125 at projection time
    gemm_nt_kernel<<<gg, TPB, 0, stream>>>(x, Wq, bq, q_ws, 0.125f, 1);
    gemm_nt_kernel<<<gg, TPB, 0, stream>>>(x, Wk, bk, k_ws, 1.0f, 1);
    gemm_nt_kernel<<<gg, TPB, 0, stream>>>(x, Wv, bv, v_ws, 1.0f, 1);

    attn_kernel<<<dim3(32, 32), TPB, 0, stream>>>(q_ws, k_ws, v_ws, a_ws);

    gemm_nt_kernel<<<gg, TPB, 0, stream>>>(a_ws, Wo, bo, out, 1.0f, 0);
}

// Round 3
// 375.833 us; speedup vs baseline: 4.9942x; 4.9942x over previous
//
#include <hip/hip_runtime.h>
#include <math.h>

#define TPB 256

typedef __attribute__((ext_vector_type(8))) short bf16x8;
typedef __attribute__((ext_vector_type(4))) float f32x4;

#define MFMA16(a, b, c) __builtin_amdgcn_mfma_f32_16x16x32_bf16((a), (b), (c), 0, 0, 0)

__device__ __forceinline__ unsigned short f2bf(float f) {
    unsigned int u = __float_as_uint(f);
    return (unsigned short)((u + 0x7FFFu + ((u >> 16) & 1u)) >> 16);
}
__device__ __forceinline__ float bf2f(unsigned short h) {
    return __uint_as_float(((unsigned int)h) << 16);
}

// ---------------------------------------------------------------------------
// Split-bf16 MFMA GEMM: out = (A @ W^T + bias) * scale
// A [8192][512] fp32, W [512][512] fp32 (torch Linear weight, rows = out ch)
// Emulates fp32 via hi/lo bf16 split: Ah*Bh + Ah*Bl + Al*Bh (3 MFMAs).
// mode 0: fp32 out [8192][512]
// mode 1: bf16 hi/lo out at [b][h][t][d]   (b=m>>11, t=m&2047, h=n>>6, d=n&63)
// mode 3: bf16 hi/lo out TRANSPOSED [b][h][d][t]  (for V -> Vt)
// Tile 128x128, BK=32, 4 waves (2x2), per-wave 64x64 = 4x4 frags of 16x16.
// LDS rows padded to 40 bf16 (80 B stride): rows r and r+8 alias -> 2-way max.
// ---------------------------------------------------------------------------
__global__ __launch_bounds__(TPB)
void gemm_split(const float* __restrict__ A, const float* __restrict__ W,
                const float* __restrict__ bias, float* __restrict__ outf,
                unsigned short* __restrict__ ohi, unsigned short* __restrict__ olo,
                float scale, int mode)
{
    __shared__ __align__(16) unsigned short Ah[128][40], Al[128][40];
    __shared__ __align__(16) unsigned short Bh[128][40], Bl[128][40];

    const int t  = threadIdx.x;
    const int m0 = blockIdx.x * 128;
    const int n0 = blockIdx.y * 128;
    const int wv = t >> 6, l = t & 63, lr = l & 15, lg = l >> 4;
    const int wm = (wv >> 1) * 64, wn = (wv & 1) * 64;

    f32x4 acc[4][4];
    #pragma unroll
    for (int i = 0; i < 4; ++i)
        #pragma unroll
        for (int j = 0; j < 4; ++j) acc[i][j] = f32x4{};

    for (int k0 = 0; k0 < 512; k0 += 32) {
        __syncthreads();
        #pragma unroll
        for (int p = 0; p < 4; ++p) {
            int id = t + TPB * p;
            int r  = id >> 3;
            int ck = (id & 7) << 2;
            float4 av = *reinterpret_cast<const float4*>(&A[(size_t)(m0 + r) * 512 + k0 + ck]);
            float4 wv4 = *reinterpret_cast<const float4*>(&W[(size_t)(n0 + r) * 512 + k0 + ck]);
            ushort4 ah, al, bh, bl;
            ah.x = f2bf(av.x);  al.x = f2bf(av.x - bf2f(ah.x));
            ah.y = f2bf(av.y);  al.y = f2bf(av.y - bf2f(ah.y));
            ah.z = f2bf(av.z);  al.z = f2bf(av.z - bf2f(ah.z));
            ah.w = f2bf(av.w);  al.w = f2bf(av.w - bf2f(ah.w));
            bh.x = f2bf(wv4.x); bl.x = f2bf(wv4.x - bf2f(bh.x));
            bh.y = f2bf(wv4.y); bl.y = f2bf(wv4.y - bf2f(bh.y));
            bh.z = f2bf(wv4.z); bl.z = f2bf(wv4.z - bf2f(bh.z));
            bh.w = f2bf(wv4.w); bl.w = f2bf(wv4.w - bf2f(bh.w));
            *reinterpret_cast<ushort4*>(&Ah[r][ck]) = ah;
            *reinterpret_cast<ushort4*>(&Al[r][ck]) = al;
            *reinterpret_cast<ushort4*>(&Bh[r][ck]) = bh;
            *reinterpret_cast<ushort4*>(&Bl[r][ck]) = bl;
        }
        __syncthreads();

        bf16x8 afh[4], afl[4], bfh[4], bfl[4];
        #pragma unroll
        for (int mi = 0; mi < 4; ++mi) {
            afh[mi] = *reinterpret_cast<const bf16x8*>(&Ah[wm + mi*16 + lr][lg*8]);
            afl[mi] = *reinterpret_cast<const bf16x8*>(&Al[wm + mi*16 + lr][lg*8]);
        }
        #pragma unroll
        for (int ni = 0; ni < 4; ++ni) {
            bfh[ni] = *reinterpret_cast<const bf16x8*>(&Bh[wn + ni*16 + lr][lg*8]);
            bfl[ni] = *reinterpret_cast<const bf16x8*>(&Bl[wn + ni*16 + lr][lg*8]);
        }
        #pragma unroll
        for (int mi = 0; mi < 4; ++mi)
            #pragma unroll
            for (int ni = 0; ni < 4; ++ni) {
                acc[mi][ni] = MFMA16(afh[mi], bfh[ni], acc[mi][ni]);
                acc[mi][ni] = MFMA16(afh[mi], bfl[ni], acc[mi][ni]);
                acc[mi][ni] = MFMA16(afl[mi], bfh[ni], acc[mi][ni]);
            }
    }

    // epilogue: D frag -> (row = mi*16 + lg*4 + j, col = ni*16 + lr)
    #pragma unroll
    for (int ni = 0; ni < 4; ++ni) {
        int gn = n0 + wn + ni*16 + lr;
        float bb = bias[gn];
        #pragma unroll
        for (int mi = 0; mi < 4; ++mi) {
            #pragma unroll
            for (int j = 0; j < 4; ++j) {
                int gm = m0 + wm + mi*16 + lg*4 + j;
                float v = acc[mi][ni][j] + bb;
                if (mode == 0) {
                    outf[(size_t)gm * 512 + gn] = v;
                } else {
                    v *= scale;
                    unsigned short h16 = f2bf(v);
                    unsigned short l16 = f2bf(v - bf2f(h16));
                    int b = gm >> 11, tt = gm & 2047, hh = gn >> 6, d = gn & 63;
                    size_t o;
                    if (mode == 3) o = (((size_t)(b*8 + hh) * 64) + d) * 2048 + tt;
                    else           o = (((size_t)(b*8 + hh) * 2048) + tt) * 64 + d;
                    ohi[o] = h16;
                    olo[o] = l16;
                }
            }
        }
    }
}

// ---------------------------------------------------------------------------
// Flash attention with multiplicative Tonnetz mask, split-bf16 MFMA.
// Q pre-scaled by 0.125 and pre-split (hi/lo) at [bh][2048][64].
// K pre-split at [bh][2048][64]; V pre-split TRANSPOSED at [bh][64][2048].
// Block: 256 threads = 4 waves; wave w owns q-rows [w*16, w*16+16).
// Per KV tile (64 keys): QK^T = 4 colblocks x 2 ksteps x 3 split-MFMAs,
// mask+online softmax in D layout, P -> bf16 hi/lo via wave-local LDS strip
// (reuses Q staging LDS), PV = 4 dblocks x 2 ksteps x 3 split-MFMAs.
// LDS rows padded to 72 bf16 (144 B): 2-way bank aliasing max (free).
// ---------------------------------------------------------------------------
__global__ __launch_bounds__(TPB)
void attn_mfma(const unsigned short* __restrict__ Qh_g, const unsigned short* __restrict__ Ql_g,
               const unsigned short* __restrict__ Kh_g, const unsigned short* __restrict__ Kl_g,
               const unsigned short* __restrict__ Vh_g, const unsigned short* __restrict__ Vl_g,
               float* __restrict__ outg)
{
    __shared__ __align__(16) unsigned short KhS[64][72], KlS[64][72];
    __shared__ __align__(16) unsigned short VhS[64][72], VlS[64][72];
    __shared__ __align__(16) unsigned short PhS[64][72], PlS[64][72];  // Q staging, then P
    __shared__ float wlut[16];

    const int t = threadIdx.x;
    // XCD-aware swizzle: 8 XCDs x 4 bh x 32 q-tiles (keeps one XCD's KV set ~L2-sized)
    int id  = blockIdx.x;
    int xcd = id & 7, seq = id >> 3;
    int bh  = xcd * 4 + (seq >> 5);
    int qt  = seq & 31;
    const int q0 = qt * 64;
    const int b  = bh >> 3, h = bh & 7;

    const int wv = t >> 6, l = t & 63, lr = l & 15, lg = l >> 4;

    if (t < 16) wlut[t] = (t <= 2) ? 1.0f : __expf(-(float)t);

    // ---- stage Q tile into PhS/PlS, read A-fragments into registers ----
    const unsigned short* Qhb = Qh_g + ((size_t)bh * 2048 + q0) * 64;
    const unsigned short* Qlb = Ql_g + ((size_t)bh * 2048 + q0) * 64;
    #pragma unroll
    for (int p = 0; p < 2; ++p) {
        int cc = t + TPB * p;
        int r  = cc >> 3;
        int c8 = (cc & 7) << 3;
        *reinterpret_cast<bf16x8*>(&PhS[r][c8]) =
            *reinterpret_cast<const bf16x8*>(&Qhb[(size_t)r * 64 + c8]);
        *reinterpret_cast<bf16x8*>(&PlS[r][c8]) =
            *reinterpret_cast<const bf16x8*>(&Qlb[(size_t)r * 64 + c8]);
    }
    __syncthreads();

    bf16x8 qfh[2], qfl[2];
    #pragma unroll
    for (int s = 0; s < 2; ++s) {
        qfh[s] = *reinterpret_cast<const bf16x8*>(&PhS[wv*16 + lr][s*32 + lg*8]);
        qfl[s] = *reinterpret_cast<const bf16x8*>(&PlS[wv*16 + lr][s*32 + lg*8]);
    }

    int qx[4], qy[4];
    #pragma unroll
    for (int j = 0; j < 4; ++j) {
        int qg = q0 + wv*16 + lg*4 + j;
        qx[j] = qg % 12;
        qy[j] = (qg / 12) % 12;
    }

    f32x4 o4[4];
    #pragma unroll
    for (int i = 0; i < 4; ++i) o4[i] = f32x4{};
    float mrow[4] = {-3.0e38f, -3.0e38f, -3.0e38f, -3.0e38f};
    float lrow[4] = {0.f, 0.f, 0.f, 0.f};

    const unsigned short* Khb = Kh_g + (size_t)bh * 2048 * 64;
    const unsigned short* Klb = Kl_g + (size_t)bh * 2048 * 64;
    const unsigned short* Vhb = Vh_g + (size_t)bh * 64 * 2048;
    const unsigned short* Vlb = Vl_g + (size_t)bh * 64 * 2048;

    for (int k0 = 0; k0 < 2048; k0 += 64) {
        __syncthreads();   // previous tile's LDS reads done
        #pragma unroll
        for (int p = 0; p < 2; ++p) {
            int cc = t + TPB * p;
            int r  = cc >> 3;
            int c8 = (cc & 7) << 3;
            *reinterpret_cast<bf16x8*>(&KhS[r][c8]) =
                *reinterpret_cast<const bf16x8*>(&Khb[(size_t)(k0 + r) * 64 + c8]);
            *reinterpret_cast<bf16x8*>(&KlS[r][c8]) =
                *reinterpret_cast<const bf16x8*>(&Klb[(size_t)(k0 + r) * 64 + c8]);
            *reinterpret_cast<bf16x8*>(&VhS[r][c8]) =
                *reinterpret_cast<const bf16x8*>(&Vhb[(size_t)r * 2048 + k0 + c8]);
            *reinterpret_cast<bf16x8*>(&VlS[r][c8]) =
                *reinterpret_cast<const bf16x8*>(&Vlb[(size_t)r * 2048 + k0 + c8]);
        }
        __syncthreads();

        // ---- S = Q K^T, split 3-MFMA ----
        f32x4 s4[4];
        #pragma unroll
        for (int c = 0; c < 4; ++c) {
            s4[c] = f32x4{};
            #pragma unroll
            for (int s = 0; s < 2; ++s) {
                bf16x8 kh = *reinterpret_cast<const bf16x8*>(&KhS[c*16 + lr][s*32 + lg*8]);
                bf16x8 kl = *reinterpret_cast<const bf16x8*>(&KlS[c*16 + lr][s*32 + lg*8]);
                s4[c] = MFMA16(qfh[s], kh, s4[c]);
                s4[c] = MFMA16(qfh[s], kl, s4[c]);
                s4[c] = MFMA16(qfl[s], kh, s4[c]);
            }
        }

        // ---- multiplicative Tonnetz mask (D layout: row q = lg*4+j, col k = c*16+lr)
        #pragma unroll
        for (int c = 0; c < 4; ++c) {
            int kk = k0 + c*16 + lr;
            int kx = kk % 12, ky = (kk / 12) % 12;
            #pragma unroll
            for (int j = 0; j < 4; ++j) {
                int dx = qx[j] - kx; dx = dx < 0 ? -dx : dx; dx = (12 - dx < dx) ? 12 - dx : dx;
                int dy = qy[j] - ky; dy = dy < 0 ? -dy : dy; dy = (12 - dy < dy) ? 12 - dy : dy;
                s4[c][j] *= wlut[dx + dy];
            }
        }

        // ---- online softmax (per q-row: 4 in-reg cols + 16-lane shfl reduce) ----
        float scj[4];
        #pragma unroll
        for (int j = 0; j < 4; ++j) {
            float rmax = fmaxf(fmaxf(s4[0][j], s4[1][j]), fmaxf(s4[2][j], s4[3][j]));
            rmax = fmaxf(rmax, __shfl_xor(rmax, 1, 16));
            rmax = fmaxf(rmax, __shfl_xor(rmax, 2, 16));
            rmax = fmaxf(rmax, __shfl_xor(rmax, 4, 16));
            rmax = fmaxf(rmax, __shfl_xor(rmax, 8, 16));
            float mnew = fmaxf(mrow[j], rmax);
            float sc   = __expf(mrow[j] - mnew);
            mrow[j] = mnew;
            scj[j]  = sc;
            float rs = 0.f;
            #pragma unroll
            for (int c = 0; c < 4; ++c) {
                float pv = __expf(s4[c][j] - mnew);
                unsigned short ph = f2bf(pv);
                unsigned short pl = f2bf(pv - bf2f(ph));
                PhS[wv*16 + lg*4 + j][c*16 + lr] = ph;   // wave-local strip
                PlS[wv*16 + lg*4 + j][c*16 + lr] = pl;
                rs += pv;
            }
            rs += __shfl_xor(rs, 1, 16);
            rs += __shfl_xor(rs, 2, 16);
            rs += __shfl_xor(rs, 4, 16);
            rs += __shfl_xor(rs, 8, 16);
            lrow[j] = lrow[j] * sc + rs;
        }

        #pragma unroll
        for (int db = 0; db < 4; ++db)
            #pragma unroll
            for (int j = 0; j < 4; ++j) o4[db][j] *= scj[j];

        // ---- PV: A = P (wave-local LDS round-trip), B = Vt, split 3-MFMA ----
        bf16x8 pfh[2], pfl[2];
        #pragma unroll
        for (int s = 0; s < 2; ++s) {
            pfh[s] = *reinterpret_cast<const bf16x8*>(&PhS[wv*16 + lr][s*32 + lg*8]);
            pfl[s] = *reinterpret_cast<const bf16x8*>(&PlS[wv*16 + lr][s*32 + lg*8]);
        }
        #pragma unroll
        for (int db = 0; db < 4; ++db) {
            #pragma unroll
            for (int s = 0; s < 2; ++s) {
                bf16x8 vh = *reinterpret_cast<const bf16x8*>(&VhS[db*16 + lr][s*32 + lg*8]);
                bf16x8 vl = *reinterpret_cast<const bf16x8*>(&VlS[db*16 + lr][s*32 + lg*8]);
                o4[db] = MFMA16(pfh[s], vh, o4[db]);
                o4[db] = MFMA16(pfh[s], vl, o4[db]);
                o4[db] = MFMA16(pfl[s], vh, o4[db]);
            }
        }
    }

    // ---- finalize: /l, write [B][T][C] fp32 (input of out-projection) ----
    #pragma unroll
    for (int j = 0; j < 4; ++j) lrow[j] = 1.0f / lrow[j];
    #pragma unroll
    for (int db = 0; db < 4; ++db) {
        #pragma unroll
        for (int j = 0; j < 4; ++j) {
            int tg = q0 + wv*16 + lg*4 + j;
            int cg = h*64 + db*16 + lr;
            outg[((size_t)b * 2048 + tg) * 512 + cg] = o4[db][j] * lrow[j];
        }
    }
}

// ---------------------------------------------------------------------------
extern "C" void kernel_launch(void* const* d_in, const int* in_sizes, int n_in,
                              void* d_out, int out_size, void* d_ws, size_t ws_size,
                              hipStream_t stream)
{
    (void)in_sizes; (void)n_in; (void)out_size; (void)ws_size;
    const float* x  = (const float*)d_in[0];
    const float* Wq = (const float*)d_in[1];
    const float* bq = (const float*)d_in[2];
    const float* Wk = (const float*)d_in[3];
    const float* bk = (const float*)d_in[4];
    const float* Wv = (const float*)d_in[5];
    const float* bv = (const float*)d_in[6];
    const float* Wo = (const float*)d_in[7];
    const float* bo = (const float*)d_in[8];
    float* out = (float*)d_out;

    // workspace layout (64 MB total, same footprint round 1 proved):
    //   a_ws fp32 [8192*512]          16,777,216 B
    //   Qh,Ql,Kh,Kl,Vh,Vl bf16 each    8,388,608 B  (4*8*2048*64)
    char* ws = (char*)d_ws;
    float* a_ws = (float*)ws;
    unsigned short* Qh = (unsigned short*)(ws + 16777216);
    unsigned short* Ql = Qh + 4194304;
    unsigned short* Kh = Ql + 4194304;
    unsigned short* Kl = Kh + 4194304;
    unsigned short* Vh = Kl + 4194304;
    unsigned short* Vl = Vh + 4194304;

    dim3 gg(64, 4);
    // Q scaled by 1/sqrt(dk)=0.125 at projection time (after bias)
    gemm_split<<<gg, TPB, 0, stream>>>(x, Wq, bq, nullptr, Qh, Ql, 0.125f, 1);
    gemm_split<<<gg, TPB, 0, stream>>>(x, Wk, bk, nullptr, Kh, Kl, 1.0f,   1);
    gemm_split<<<gg, TPB, 0, stream>>>(x, Wv, bv, nullptr, Vh, Vl, 1.0f,   3);

    attn_mfma<<<1024, TPB, 0, stream>>>(Qh, Ql, Kh, Kl, Vh, Vl, a_ws);

    gemm_split<<<gg, TPB, 0, stream>>>(a_ws, Wo, bo, out, nullptr, nullptr, 1.0f, 0);
}

// Round 4
// 287.097 us; speedup vs baseline: 6.5378x; 1.3091x over previous
//
#include <hip/hip_runtime.h>
#include <math.h>

#define TPB 256
#define QSCALE 0.1803368801111204f   // 0.125 * log2(e): folds 1/sqrt(dk) and exp->exp2

typedef __attribute__((ext_vector_type(8))) short bf16x8;
typedef __attribute__((ext_vector_type(8))) unsigned short u16x8;
typedef __attribute__((ext_vector_type(4))) float f32x4;
typedef unsigned short u16;

#define MFMA16(a, b, c) __builtin_amdgcn_mfma_f32_16x16x32_bf16((a), (b), (c), 0, 0, 0)

__device__ __forceinline__ u16 f2bf(float f) {           // RNE
    unsigned int u = __float_as_uint(f);
    return (u16)((u + 0x7FFFu + ((u >> 16) & 1u)) >> 16);
}
__device__ __forceinline__ float bf2f(u16 h) {
    return __uint_as_float(((unsigned int)h) << 16);
}

// ---------------------------------------------------------------------------
// Pre-split fp32 -> (hi,lo) bf16, optional scale. 8 elems/thread.
// ---------------------------------------------------------------------------
__global__ __launch_bounds__(TPB)
void presplit(const float* __restrict__ in, u16* __restrict__ oh,
              u16* __restrict__ ol, float scale)
{
    size_t i = ((size_t)blockIdx.x * TPB + threadIdx.x) * 8;
    float4 a = *reinterpret_cast<const float4*>(in + i);
    float4 b = *reinterpret_cast<const float4*>(in + i + 4);
    float v[8] = {a.x, a.y, a.z, a.w, b.x, b.y, b.z, b.w};
    u16x8 hv, lv;
    #pragma unroll
    for (int k = 0; k < 8; ++k) {
        float s = v[k] * scale;
        u16 h = f2bf(s);
        hv[k] = h;
        lv[k] = f2bf(s - bf2f(h));
    }
    *reinterpret_cast<u16x8*>(oh + i) = hv;
    *reinterpret_cast<u16x8*>(ol + i) = lv;
}

// 4 weights [512][512] -> concatenated hi/lo, Wq scaled by QSCALE.
__global__ __launch_bounds__(TPB)
void presplit_w(const float* __restrict__ w0, const float* __restrict__ w1,
                const float* __restrict__ w2, const float* __restrict__ w3,
                u16* __restrict__ WH, u16* __restrict__ WL)
{
    int y = blockIdx.y;
    const float* src = (y == 0) ? w0 : (y == 1) ? w1 : (y == 2) ? w2 : w3;
    float sc = (y == 0) ? QSCALE : 1.0f;
    size_t base = (size_t)y * 262144;
    size_t i = ((size_t)blockIdx.x * TPB + threadIdx.x) * 8;
    float4 a = *reinterpret_cast<const float4*>(src + i);
    float4 b = *reinterpret_cast<const float4*>(src + i + 4);
    float v[8] = {a.x, a.y, a.z, a.w, b.x, b.y, b.z, b.w};
    u16x8 hv, lv;
    #pragma unroll
    for (int k = 0; k < 8; ++k) {
        float s = v[k] * sc;
        u16 h = f2bf(s);
        hv[k] = h;
        lv[k] = f2bf(s - bf2f(h));
    }
    *reinterpret_cast<u16x8*>(WH + base + i) = hv;
    *reinterpret_cast<u16x8*>(WL + base + i) = lv;
}

// ---------------------------------------------------------------------------
// Split-bf16 GEMM on PRE-SPLIT operands: out = A @ B^T + bias*bscale
// A hi/lo [8192][512] bf16, B hi/lo [512][512] bf16 (torch W rows = out ch).
// 3-term: Ah*Bh + Ah*Bl + Al*Bh.
// mode 0: fp32 out [8192][512]
// mode 1: hi/lo bf16 out [b][h][t][d]
// mode 3: single bf16 out TRANSPOSED [b][h][d][t]
// Tile 128x128, BK=32, 4 waves (2x2), per-wave 64x64 = 4x4 frags.
// ---------------------------------------------------------------------------
__global__ __launch_bounds__(TPB)
void gemm_pre(const u16* __restrict__ Ah_g, const u16* __restrict__ Al_g,
              const u16* __restrict__ Bh_g, const u16* __restrict__ Bl_g,
              const float* __restrict__ bias, float bscale,
              float* __restrict__ outf, u16* __restrict__ ohi, u16* __restrict__ olo,
              int mode)
{
    __shared__ __align__(16) u16 AhS[128][40], AlS[128][40];
    __shared__ __align__(16) u16 BhS[128][40], BlS[128][40];

    const int t  = threadIdx.x;
    const int m0 = blockIdx.x * 128;
    const int n0 = blockIdx.y * 128;
    const int wv = t >> 6, l = t & 63, lr = l & 15, lg = l >> 4;
    const int wm = (wv >> 1) * 64, wn = (wv & 1) * 64;

    f32x4 acc[4][4];
    #pragma unroll
    for (int i = 0; i < 4; ++i)
        #pragma unroll
        for (int j = 0; j < 4; ++j) acc[i][j] = f32x4{};

    for (int k0 = 0; k0 < 512; k0 += 32) {
        __syncthreads();
        #pragma unroll
        for (int p = 0; p < 2; ++p) {
            int cc = t + TPB * p;
            int r = cc >> 2, c8 = (cc & 3) << 3;
            *reinterpret_cast<bf16x8*>(&AhS[r][c8]) =
                *reinterpret_cast<const bf16x8*>(&Ah_g[(size_t)(m0 + r) * 512 + k0 + c8]);
            *reinterpret_cast<bf16x8*>(&AlS[r][c8]) =
                *reinterpret_cast<const bf16x8*>(&Al_g[(size_t)(m0 + r) * 512 + k0 + c8]);
            *reinterpret_cast<bf16x8*>(&BhS[r][c8]) =
                *reinterpret_cast<const bf16x8*>(&Bh_g[(size_t)(n0 + r) * 512 + k0 + c8]);
            *reinterpret_cast<bf16x8*>(&BlS[r][c8]) =
                *reinterpret_cast<const bf16x8*>(&Bl_g[(size_t)(n0 + r) * 512 + k0 + c8]);
        }
        __syncthreads();

        bf16x8 afh[4], afl[4], bfh[4], bfl[4];
        #pragma unroll
        for (int mi = 0; mi < 4; ++mi) {
            afh[mi] = *reinterpret_cast<const bf16x8*>(&AhS[wm + mi*16 + lr][lg*8]);
            afl[mi] = *reinterpret_cast<const bf16x8*>(&AlS[wm + mi*16 + lr][lg*8]);
        }
        #pragma unroll
        for (int ni = 0; ni < 4; ++ni) {
            bfh[ni] = *reinterpret_cast<const bf16x8*>(&BhS[wn + ni*16 + lr][lg*8]);
            bfl[ni] = *reinterpret_cast<const bf16x8*>(&BlS[wn + ni*16 + lr][lg*8]);
        }
        #pragma unroll
        for (int mi = 0; mi < 4; ++mi)
            #pragma unroll
            for (int ni = 0; ni < 4; ++ni) {
                acc[mi][ni] = MFMA16(afh[mi], bfh[ni], acc[mi][ni]);
                acc[mi][ni] = MFMA16(afh[mi], bfl[ni], acc[mi][ni]);
                acc[mi][ni] = MFMA16(afl[mi], bfh[ni], acc[mi][ni]);
            }
    }

    // epilogue: D frag -> (row = mi*16 + lg*4 + j, col = ni*16 + lr)
    #pragma unroll
    for (int ni = 0; ni < 4; ++ni) {
        int gn = n0 + wn + ni*16 + lr;
        float bb = bias[gn] * bscale;
        #pragma unroll
        for (int mi = 0; mi < 4; ++mi) {
            #pragma unroll
            for (int j = 0; j < 4; ++j) {
                int gm = m0 + wm + mi*16 + lg*4 + j;
                float v = acc[mi][ni][j] + bb;
                if (mode == 0) {
                    outf[(size_t)gm * 512 + gn] = v;
                } else if (mode == 1) {
                    u16 h16 = f2bf(v);
                    u16 l16 = f2bf(v - bf2f(h16));
                    int b = gm >> 11, tt = gm & 2047, hh = gn >> 6, d = gn & 63;
                    size_t o = (((size_t)(b*8 + hh) * 2048) + tt) * 64 + d;
                    ohi[o] = h16;
                    olo[o] = l16;
                } else {  // mode 3: single bf16, transposed [b][h][d][t]
                    int b = gm >> 11, tt = gm & 2047, hh = gn >> 6, d = gn & 63;
                    ohi[(((size_t)(b*8 + hh) * 64) + d) * 2048 + tt] = f2bf(v);
                }
            }
        }
    }
}

// ---------------------------------------------------------------------------
// Flash attention, no-max softmax (scores bounded), multiplicative Tonnetz
// mask via float torus-distance + __shfl LUT (bpermute, conflict-free).
// Q hi/lo [bh][2048][64] pre-scaled by 0.125*log2e; K hi/lo same layout;
// V single bf16 TRANSPOSED [bh][64][2048].
// QK^T = 3-term split (24 MFMA/tile/wave); PV = single (8 MFMA).
// Output: hi/lo bf16 [8192][512] (A-operand of out-projection).
// LDS 36.9 KB -> 4 blocks/CU.
// ---------------------------------------------------------------------------
__global__ __launch_bounds__(TPB)
void attn_mfma(const u16* __restrict__ Qh_g, const u16* __restrict__ Ql_g,
               const u16* __restrict__ Kh_g, const u16* __restrict__ Kl_g,
               const u16* __restrict__ Vt_g,
               u16* __restrict__ AOh, u16* __restrict__ AOl)
{
    __shared__ __align__(16) u16 KhS[64][72], KlS[64][72];
    __shared__ __align__(16) u16 VS[64][72], PS[64][72];

    const int t = threadIdx.x;
    // XCD-aware swizzle: 8 XCDs x 4 bh x 32 q-tiles
    int id  = blockIdx.x;
    int xcd = id & 7, seq = id >> 3;
    int bh  = xcd * 4 + (seq >> 5);
    int qt  = seq & 31;
    const int q0 = qt * 64;
    const int b  = bh >> 3, h = bh & 7;
    const int wv = t >> 6, l = t & 63, lr = l & 15, lg = l >> 4;

    // lane l holds mask weight for distance l (only 0..12 used)
    const float wreg = (l <= 2) ? 1.0f : __expf(-(float)l);

    // Q fragments straight from global (once per block)
    const u16* Qhb = Qh_g + ((size_t)bh * 2048 + q0) * 64;
    const u16* Qlb = Ql_g + ((size_t)bh * 2048 + q0) * 64;
    bf16x8 qfh[2], qfl[2];
    #pragma unroll
    for (int s = 0; s < 2; ++s) {
        qfh[s] = *reinterpret_cast<const bf16x8*>(&Qhb[(size_t)(wv*16 + lr) * 64 + s*32 + lg*8]);
        qfl[s] = *reinterpret_cast<const bf16x8*>(&Qlb[(size_t)(wv*16 + lr) * 64 + s*32 + lg*8]);
    }

    float qxf[4], qyf[4];
    #pragma unroll
    for (int j = 0; j < 4; ++j) {
        int qg = q0 + wv*16 + lg*4 + j;
        qxf[j] = (float)(qg % 12);
        qyf[j] = (float)((qg / 12) % 12);
    }

    f32x4 o4[4];
    #pragma unroll
    for (int i = 0; i < 4; ++i) o4[i] = f32x4{};
    float lrow[4] = {0.f, 0.f, 0.f, 0.f};

    const u16* Khb = Kh_g + (size_t)bh * 2048 * 64;
    const u16* Klb = Kl_g + (size_t)bh * 2048 * 64;
    const u16* Vtb = Vt_g + (size_t)bh * 64 * 2048;

    for (int k0 = 0; k0 < 2048; k0 += 64) {
        __syncthreads();   // previous tile's K/V frag reads done
        #pragma unroll
        for (int p = 0; p < 2; ++p) {
            int cc = t + TPB * p;
            int r = cc >> 3, c8 = (cc & 7) << 3;
            *reinterpret_cast<bf16x8*>(&KhS[r][c8]) =
                *reinterpret_cast<const bf16x8*>(&Khb[(size_t)(k0 + r) * 64 + c8]);
            *reinterpret_cast<bf16x8*>(&KlS[r][c8]) =
                *reinterpret_cast<const bf16x8*>(&Klb[(size_t)(k0 + r) * 64 + c8]);
            *reinterpret_cast<bf16x8*>(&VS[r][c8]) =
                *reinterpret_cast<const bf16x8*>(&Vtb[(size_t)r * 2048 + k0 + c8]);
        }
        __syncthreads();

        // ---- S = Q K^T (3-term split MFMA), s' already includes log2e/8 ----
        f32x4 s4[4];
        #pragma unroll
        for (int c = 0; c < 4; ++c) {
            s4[c] = f32x4{};
            #pragma unroll
            for (int s = 0; s < 2; ++s) {
                bf16x8 kh = *reinterpret_cast<const bf16x8*>(&KhS[c*16 + lr][s*32 + lg*8]);
                bf16x8 kl = *reinterpret_cast<const bf16x8*>(&KlS[c*16 + lr][s*32 + lg*8]);
                s4[c] = MFMA16(qfh[s], kh, s4[c]);
                s4[c] = MFMA16(qfh[s], kl, s4[c]);
                s4[c] = MFMA16(qfl[s], kh, s4[c]);
            }
        }

        // ---- mask coords per colblock (int mod only 4x/tile) ----
        float kxf[4], kyf[4];
        #pragma unroll
        for (int c = 0; c < 4; ++c) {
            int kk = k0 + c*16 + lr;
            kxf[c] = (float)(kk % 12);
            kyf[c] = (float)((kk / 12) % 12);
        }

        // ---- p = exp2(s*w); no max subtraction; P truncated to bf16 ----
        #pragma unroll
        for (int j = 0; j < 4; ++j) {
            float rs = 0.f;
            #pragma unroll
            for (int c = 0; c < 4; ++c) {
                float dx = 6.0f - fabsf(fabsf(qxf[j] - kxf[c]) - 6.0f);
                float dy = 6.0f - fabsf(fabsf(qyf[j] - kyf[c]) - 6.0f);
                int idx = (int)(dx + dy);
                float w = __shfl(wreg, idx, 64);
                float p = exp2f(s4[c][j] * w);
                unsigned int pu = __float_as_uint(p) >> 16;   // truncate to bf16
                PS[wv*16 + lg*4 + j][c*16 + lr] = (u16)pu;
                rs += __uint_as_float(pu << 16);              // sum the truncated value
            }
            rs += __shfl_xor(rs, 1, 16);
            rs += __shfl_xor(rs, 2, 16);
            rs += __shfl_xor(rs, 4, 16);
            rs += __shfl_xor(rs, 8, 16);
            lrow[j] += rs;
        }

        // ---- PV (single bf16 x single bf16), wave-local P round-trip ----
        bf16x8 pf[2];
        #pragma unroll
        for (int s = 0; s < 2; ++s)
            pf[s] = *reinterpret_cast<const bf16x8*>(&PS[wv*16 + lr][s*32 + lg*8]);
        #pragma unroll
        for (int db = 0; db < 4; ++db) {
            #pragma unroll
            for (int s = 0; s < 2; ++s) {
                bf16x8 vv = *reinterpret_cast<const bf16x8*>(&VS[db*16 + lr][s*32 + lg*8]);
                o4[db] = MFMA16(pf[s], vv, o4[db]);
            }
        }
    }

    // ---- finalize: /l, write hi/lo bf16 [8192][512] for out-projection ----
    float inv[4];
    #pragma unroll
    for (int j = 0; j < 4; ++j) inv[j] = 1.0f / lrow[j];
    #pragma unroll
    for (int db = 0; db < 4; ++db) {
        #pragma unroll
        for (int j = 0; j < 4; ++j) {
            float val = o4[db][j] * inv[j];
            u16 h16 = f2bf(val);
            u16 l16 = f2bf(val - bf2f(h16));
            size_t mrow = (size_t)b * 2048 + q0 + wv*16 + lg*4 + j;
            size_t off = mrow * 512 + h*64 + db*16 + lr;
            AOh[off] = h16;
            AOl[off] = l16;
        }
    }
}

// ---------------------------------------------------------------------------
extern "C" void kernel_launch(void* const* d_in, const int* in_sizes, int n_in,
                              void* d_out, int out_size, void* d_ws, size_t ws_size,
                              hipStream_t stream)
{
    (void)in_sizes; (void)n_in; (void)out_size; (void)ws_size;
    const float* x  = (const float*)d_in[0];
    const float* Wq = (const float*)d_in[1];
    const float* bq = (const float*)d_in[2];
    const float* Wk = (const float*)d_in[3];
    const float* bk = (const float*)d_in[4];
    const float* Wv = (const float*)d_in[5];
    const float* bv = (const float*)d_in[6];
    const float* Wo = (const float*)d_in[7];
    const float* bo = (const float*)d_in[8];
    float* out = (float*)d_out;

    // workspace (60 MB of the >=64 MB proven in round 1):
    //   Xh,Xl       2 x 8 MB   (reused as AOh,AOl after QKV GEMMs)
    //   WH,WL       2 x 2 MB   (4 weights hi/lo, Wq pre-scaled by 0.125*log2e)
    //   Qh,Ql,Kh,Kl 4 x 8 MB
    //   Vt          1 x 8 MB   (single bf16, transposed [bh][64][2048])
    u16* Xh = (u16*)d_ws;
    u16* Xl = Xh + 4194304;
    u16* WH = Xl + 4194304;
    u16* WL = WH + 1048576;
    u16* Qh = WL + 1048576;
    u16* Ql = Qh + 4194304;
    u16* Kh = Ql + 4194304;
    u16* Kl = Kh + 4194304;
    u16* Vt = Kl + 4194304;
    u16* AOh = Xh;
    u16* AOl = Xl;

    presplit<<<2048, TPB, 0, stream>>>(x, Xh, Xl, 1.0f);
    presplit_w<<<dim3(128, 4), TPB, 0, stream>>>(Wq, Wk, Wv, Wo, WH, WL);

    dim3 gg(64, 4);
    gemm_pre<<<gg, TPB, 0, stream>>>(Xh, Xl, WH,          WL,          bq, QSCALE, nullptr, Qh, Ql, 1);
    gemm_pre<<<gg, TPB, 0, stream>>>(Xh, Xl, WH + 262144, WL + 262144, bk, 1.0f,   nullptr, Kh, Kl, 1);
    gemm_pre<<<gg, TPB, 0, stream>>>(Xh, Xl, WH + 524288, WL + 524288, bv, 1.0f,   nullptr, Vt, nullptr, 3);

    attn_mfma<<<1024, TPB, 0, stream>>>(Qh, Ql, Kh, Kl, Vt, AOh, AOl);

    gemm_pre<<<gg, TPB, 0, stream>>>(AOh, AOl, WH + 786432, WL + 786432, bo, 1.0f, out, nullptr, nullptr, 0);
}

// Round 6
// 235.491 us; speedup vs baseline: 7.9705x; 1.2191x over previous
//
#include <hip/hip_runtime.h>
#include <math.h>

#define TPB 256
#define QSCALE 0.1803368801111204f   // 0.125 * log2(e): folds 1/sqrt(dk) and exp->exp2

typedef __attribute__((ext_vector_type(8))) short bf16x8;
typedef __attribute__((ext_vector_type(8))) unsigned short u16x8;
typedef __attribute__((ext_vector_type(4))) float f32x4;
typedef __attribute__((ext_vector_type(16))) float f32x16;
typedef __attribute__((ext_vector_type(4))) unsigned int u32x4;
typedef __attribute__((ext_vector_type(2))) unsigned int u32x2;
typedef unsigned short u16;
typedef unsigned int u32;

#define MFMA16(a, b, c) __builtin_amdgcn_mfma_f32_16x16x32_bf16((a), (b), (c), 0, 0, 0)
#define MFMA32(a, b, c) __builtin_amdgcn_mfma_f32_32x32x16_bf16((a), (b), (c), 0, 0, 0)

__device__ __forceinline__ u16 f2bf(float f) {           // RNE
    unsigned int u = __float_as_uint(f);
    return (u16)((u + 0x7FFFu + ((u >> 16) & 1u)) >> 16);
}
__device__ __forceinline__ float bf2f(u16 h) {
    return __uint_as_float(((unsigned int)h) << 16);
}

// ---------------------------------------------------------------------------
// Pre-split fp32 -> (hi,lo) bf16. 8 elems/thread.
// ---------------------------------------------------------------------------
__global__ __launch_bounds__(TPB)
void presplit(const float* __restrict__ in, u16* __restrict__ oh,
              u16* __restrict__ ol, float scale)
{
    size_t i = ((size_t)blockIdx.x * TPB + threadIdx.x) * 8;
    float4 a = *reinterpret_cast<const float4*>(in + i);
    float4 b = *reinterpret_cast<const float4*>(in + i + 4);
    float v[8] = {a.x, a.y, a.z, a.w, b.x, b.y, b.z, b.w};
    u16x8 hv, lv;
    #pragma unroll
    for (int k = 0; k < 8; ++k) {
        float s = v[k] * scale;
        u16 h = f2bf(s);
        hv[k] = h;
        lv[k] = f2bf(s - bf2f(h));
    }
    *reinterpret_cast<u16x8*>(oh + i) = hv;
    *reinterpret_cast<u16x8*>(ol + i) = lv;
}

// 4 weights [512][512] -> concatenated hi/lo, Wq scaled by QSCALE.
__global__ __launch_bounds__(TPB)
void presplit_w(const float* __restrict__ w0, const float* __restrict__ w1,
                const float* __restrict__ w2, const float* __restrict__ w3,
                u16* __restrict__ WH, u16* __restrict__ WL)
{
    int y = blockIdx.y;
    const float* src = (y == 0) ? w0 : (y == 1) ? w1 : (y == 2) ? w2 : w3;
    float sc = (y == 0) ? QSCALE : 1.0f;
    size_t base = (size_t)y * 262144;
    size_t i = ((size_t)blockIdx.x * TPB + threadIdx.x) * 8;
    float4 a = *reinterpret_cast<const float4*>(src + i);
    float4 b = *reinterpret_cast<const float4*>(src + i + 4);
    float v[8] = {a.x, a.y, a.z, a.w, b.x, b.y, b.z, b.w};
    u16x8 hv, lv;
    #pragma unroll
    for (int k = 0; k < 8; ++k) {
        float s = v[k] * sc;
        u16 h = f2bf(s);
        hv[k] = h;
        lv[k] = f2bf(s - bf2f(h));
    }
    *reinterpret_cast<u16x8*>(WH + base + i) = hv;
    *reinterpret_cast<u16x8*>(WL + base + i) = lv;
}

// ---------------------------------------------------------------------------
// Tonnetz torus distance, nibble-packed, in the 32x32 MFMA S^T D-layout.
// mws u32: [(qt*32+kt)*4 + w][128]: lane l -> 2 words (r=0..7, r=8..15).
// q = qt*64 + (w&1)*32 + (l&31); key = kt*64 + (w>>1)*32 + pat(r, l>>5).
// ---------------------------------------------------------------------------
__global__ __launch_bounds__(TPB)
void mask_pre(u32* __restrict__ mws)
{
    int bid = blockIdx.x;            // 1024 = 32 qt x 32 kt
    int qt = bid >> 5, kt = bid & 31;
    int t = threadIdx.x, w = t >> 6, l = t & 63;
    int q = qt * 64 + (w & 1) * 32 + (l & 31);
    int qx = q % 12, qy = (q / 12) % 12;
    int hh = l >> 5;
    u32 words[2] = {0u, 0u};
    #pragma unroll
    for (int r = 0; r < 16; ++r) {
        int key = kt * 64 + (w >> 1) * 32 + (r & 3) + 8 * (r >> 2) + 4 * hh;
        int kx = key % 12, ky = (key / 12) % 12;
        int dx = qx - kx; dx = dx < 0 ? -dx : dx; dx = dx < 12 - dx ? dx : 12 - dx;
        int dy = qy - ky; dy = dy < 0 ? -dy : dy; dy = dy < 12 - dy ? dy : 12 - dy;
        u32 d = (u32)(dx + dy);
        words[r >> 3] |= d << ((r & 7) * 4);
    }
    size_t base = (size_t)(bid * 4 + w) * 128 + l * 2;
    mws[base]     = words[0];
    mws[base + 1] = words[1];
}

// ---------------------------------------------------------------------------
// Split-bf16 GEMM on PRE-SPLIT operands: out = A @ B^T + bias*bscale
// mode 0: fp32 out [8192][512]
// mode 1: hi/lo bf16 out [b][h][t][d]
// mode 2: single bf16 out [b][h][t][d]          (K)
// mode 3: single bf16 out TRANSPOSED [b][h][d][t] (V)
// ---------------------------------------------------------------------------
__global__ __launch_bounds__(TPB)
void gemm_pre(const u16* __restrict__ Ah_g, const u16* __restrict__ Al_g,
              const u16* __restrict__ Bh_g, const u16* __restrict__ Bl_g,
              const float* __restrict__ bias, float bscale,
              float* __restrict__ outf, u16* __restrict__ ohi, u16* __restrict__ olo,
              int mode)
{
    __shared__ __align__(16) u16 AhS[128][40], AlS[128][40];
    __shared__ __align__(16) u16 BhS[128][40], BlS[128][40];

    const int t  = threadIdx.x;
    const int m0 = blockIdx.x * 128;
    const int n0 = blockIdx.y * 128;
    const int wv = t >> 6, l = t & 63, lr = l & 15, lg = l >> 4;
    const int wm = (wv >> 1) * 64, wn = (wv & 1) * 64;

    f32x4 acc[4][4];
    #pragma unroll
    for (int i = 0; i < 4; ++i)
        #pragma unroll
        for (int j = 0; j < 4; ++j) acc[i][j] = f32x4{};

    for (int k0 = 0; k0 < 512; k0 += 32) {
        __syncthreads();
        #pragma unroll
        for (int p = 0; p < 2; ++p) {
            int cc = t + TPB * p;
            int r = cc >> 2, c8 = (cc & 3) << 3;
            *reinterpret_cast<bf16x8*>(&AhS[r][c8]) =
                *reinterpret_cast<const bf16x8*>(&Ah_g[(size_t)(m0 + r) * 512 + k0 + c8]);
            *reinterpret_cast<bf16x8*>(&AlS[r][c8]) =
                *reinterpret_cast<const bf16x8*>(&Al_g[(size_t)(m0 + r) * 512 + k0 + c8]);
            *reinterpret_cast<bf16x8*>(&BhS[r][c8]) =
                *reinterpret_cast<const bf16x8*>(&Bh_g[(size_t)(n0 + r) * 512 + k0 + c8]);
            *reinterpret_cast<bf16x8*>(&BlS[r][c8]) =
                *reinterpret_cast<const bf16x8*>(&Bl_g[(size_t)(n0 + r) * 512 + k0 + c8]);
        }
        __syncthreads();

        bf16x8 afh[4], afl[4], bfh[4], bfl[4];
        #pragma unroll
        for (int mi = 0; mi < 4; ++mi) {
            afh[mi] = *reinterpret_cast<const bf16x8*>(&AhS[wm + mi*16 + lr][lg*8]);
            afl[mi] = *reinterpret_cast<const bf16x8*>(&AlS[wm + mi*16 + lr][lg*8]);
        }
        #pragma unroll
        for (int ni = 0; ni < 4; ++ni) {
            bfh[ni] = *reinterpret_cast<const bf16x8*>(&BhS[wn + ni*16 + lr][lg*8]);
            bfl[ni] = *reinterpret_cast<const bf16x8*>(&BlS[wn + ni*16 + lr][lg*8]);
        }
        #pragma unroll
        for (int mi = 0; mi < 4; ++mi)
            #pragma unroll
            for (int ni = 0; ni < 4; ++ni) {
                acc[mi][ni] = MFMA16(afh[mi], bfh[ni], acc[mi][ni]);
                acc[mi][ni] = MFMA16(afh[mi], bfl[ni], acc[mi][ni]);
                acc[mi][ni] = MFMA16(afl[mi], bfh[ni], acc[mi][ni]);
            }
    }

    #pragma unroll
    for (int ni = 0; ni < 4; ++ni) {
        int gn = n0 + wn + ni*16 + lr;
        float bb = bias[gn] * bscale;
        #pragma unroll
        for (int mi = 0; mi < 4; ++mi) {
            #pragma unroll
            for (int j = 0; j < 4; ++j) {
                int gm = m0 + wm + mi*16 + lg*4 + j;
                float v = acc[mi][ni][j] + bb;
                if (mode == 0) {
                    outf[(size_t)gm * 512 + gn] = v;
                } else {
                    int b = gm >> 11, tt = gm & 2047, hh = gn >> 6, d = gn & 63;
                    if (mode == 1) {
                        u16 h16 = f2bf(v);
                        size_t o = (((size_t)(b*8 + hh) * 2048) + tt) * 64 + d;
                        ohi[o] = h16;
                        olo[o] = f2bf(v - bf2f(h16));
                    } else if (mode == 2) {
                        ohi[(((size_t)(b*8 + hh) * 2048) + tt) * 64 + d] = f2bf(v);
                    } else {  // mode 3: transposed [b][h][d][t]
                        ohi[(((size_t)(b*8 + hh) * 64) + d) * 2048 + tt] = f2bf(v);
                    }
                }
            }
        }
    }
}

// ---------------------------------------------------------------------------
// Flash attention, 32x32x16 MFMA, swapped QK^T (S^T = K Q^T), no-max softmax.
// Q hi/lo [bh][2048][64] pre-scaled by 0.125*log2e, held in registers.
// K single bf16 [bh][2048][64]; V single bf16 transposed [bh][64][2048].
// Mask: 4-bit torus distances in D-layout, LUT via lane-shuffle.
// P built in-register; lane-half exchange via __shfl_xor(.,32) (known-good
// semantics — replaces the round-5 v_permlane32_swap whose operand/direction
// semantics could not be verified and matched the observed close-key error).
// Each wave accumulates partial-O over its 32-key half; one LDS merge at end.
// LDS: 16 KB K/V tiles (stride 64, 16B-slot XOR swizzle) + merge scratch.
// ---------------------------------------------------------------------------
__device__ __forceinline__ int lidx(int row, int col) {    // col multiple of 8
    return row * 64 + (col ^ ((row & 7) << 3));
}

__global__ __launch_bounds__(TPB)
void attn32(const u16* __restrict__ Qh_g, const u16* __restrict__ Ql_g,
            const u16* __restrict__ K_g,  const u16* __restrict__ Vt_g,
            const u32* __restrict__ mws,
            u16* __restrict__ AOh, u16* __restrict__ AOl)
{
    __shared__ __align__(16) u16 SMEM[2 * 64 * 64];  // KS | VS; reused as f32 merge scratch
    __shared__ float SC[4][64];
    __shared__ float ILS[64];
    u16* KSp = SMEM;
    u16* VSp = SMEM + 64 * 64;

    const int t = threadIdx.x;
    int id  = blockIdx.x;                 // XCD swizzle: 8 XCDs x 4 bh x 32 q-tiles
    int xcd = id & 7, seq = id >> 3;
    int bh  = xcd * 4 + (seq >> 5);
    int qt  = seq & 31;
    const int q0 = qt * 64;
    const int b = bh >> 3, h = bh & 7;
    const int w = t >> 6, l = t & 63, lh = l >> 5, l31 = l & 31;
    const int kh = w >> 1, qh = w & 1;

    // lane d holds mask weight(d) for d<=12
    const float wreg = (l <= 2) ? 1.0f : __expf(-(float)l);

    // Q B-fragments in registers: col q = q0+qh*32+l31, k(d) = ks*16+lh*8+j
    const u16* Qhb = Qh_g + ((size_t)bh * 2048 + q0 + qh * 32 + l31) * 64;
    const u16* Qlb = Ql_g + ((size_t)bh * 2048 + q0 + qh * 32 + l31) * 64;
    bf16x8 qfh[4], qfl[4];
    #pragma unroll
    for (int ks = 0; ks < 4; ++ks) {
        qfh[ks] = *reinterpret_cast<const bf16x8*>(&Qhb[ks * 16 + lh * 8]);
        qfl[ks] = *reinterpret_cast<const bf16x8*>(&Qlb[ks * 16 + lh * 8]);
    }

    const u16* Kb = K_g  + (size_t)bh * 2048 * 64;
    const u16* Vb = Vt_g + (size_t)bh * 64 * 2048;
    const int sr = t >> 2, sc = (t & 3) * 16;   // staging: row, col (coalesced global)

    // prefetch tile 0
    bf16x8 kst0 = *reinterpret_cast<const bf16x8*>(&Kb[(size_t)sr * 64 + sc]);
    bf16x8 kst1 = *reinterpret_cast<const bf16x8*>(&Kb[(size_t)sr * 64 + sc + 8]);
    bf16x8 vst0 = *reinterpret_cast<const bf16x8*>(&Vb[(size_t)sr * 2048 + sc]);
    bf16x8 vst1 = *reinterpret_cast<const bf16x8*>(&Vb[(size_t)sr * 2048 + sc + 8]);
    u32x2 mwd = *reinterpret_cast<const u32x2*>(&mws[(size_t)(qt * 32 + 0) * 512 + w * 128 + l * 2]);

    f32x16 o0 = {}, o1 = {};
    float lrow = 0.f;

    for (int kt = 0; kt < 32; ++kt) {
        __syncthreads();                          // prior tile's fragment reads done
        *reinterpret_cast<bf16x8*>(&KSp[lidx(sr, sc)])     = kst0;
        *reinterpret_cast<bf16x8*>(&KSp[lidx(sr, sc + 8)]) = kst1;
        *reinterpret_cast<bf16x8*>(&VSp[lidx(sr, sc)])     = vst0;
        *reinterpret_cast<bf16x8*>(&VSp[lidx(sr, sc + 8)]) = vst1;
        u32 mw0 = mwd.x, mw1 = mwd.y;
        __syncthreads();                          // stage visible

        if (kt < 31) {                            // prefetch next tile during compute
            int k0n = (kt + 1) * 64;
            kst0 = *reinterpret_cast<const bf16x8*>(&Kb[(size_t)(k0n + sr) * 64 + sc]);
            kst1 = *reinterpret_cast<const bf16x8*>(&Kb[(size_t)(k0n + sr) * 64 + sc + 8]);
            vst0 = *reinterpret_cast<const bf16x8*>(&Vb[(size_t)sr * 2048 + k0n + sc]);
            vst1 = *reinterpret_cast<const bf16x8*>(&Vb[(size_t)sr * 2048 + k0n + sc + 8]);
            mwd  = *reinterpret_cast<const u32x2*>(&mws[(size_t)(qt * 32 + kt + 1) * 512 + w * 128 + l * 2]);
        }

        // ---- S^T = K (Qh^T + Ql^T): rows=keys (D pattern), cols=q (lane) ----
        f32x16 st = {};
        #pragma unroll
        for (int ks = 0; ks < 4; ++ks) {
            bf16x8 kf = *reinterpret_cast<const bf16x8*>(&KSp[lidx(kh * 32 + l31, ks * 16 + lh * 8)]);
            st = MFMA32(kf, qfh[ks], st);
            st = MFMA32(kf, qfl[ks], st);
        }

        // ---- p = exp2(s * w(d)), truncate to bf16, lane-local row-sum ----
        float p[16];
        #pragma unroll
        for (int r = 0; r < 16; ++r) {
            u32 d = (((r < 8) ? mw0 : mw1) >> ((r & 7) * 4)) & 15u;
            float wgt = __shfl(wreg, (int)d, 64);
            float pv = exp2f(st[r] * wgt);
            p[r] = __uint_as_float(__float_as_uint(pv) & 0xFFFF0000u);
            lrow += p[r];
        }

        // ---- PV: build A-frags in-register (pack + shfl_xor half-exchange) ----
        // p[base+rr] holds key_off (rr&3) + 8*(rr>>2) + 4*lh (within 16ks block).
        // Lane lh needs A slots j=0..7 <-> key_off lh*8 + j:
        //  lh=0: [pk01, pk23, pk01^32, pk23^32]   (keys 0..7)
        //  lh=1: [pk45^32, pk67^32, pk45, pk67]   (keys 8..15)
        #pragma unroll
        for (int ks = 0; ks < 2; ++ks) {
            const int base = ks * 8;
            u32 pk01 = (__float_as_uint(p[base + 0]) >> 16) | __float_as_uint(p[base + 1]);
            u32 pk23 = (__float_as_uint(p[base + 2]) >> 16) | __float_as_uint(p[base + 3]);
            u32 pk45 = (__float_as_uint(p[base + 4]) >> 16) | __float_as_uint(p[base + 5]);
            u32 pk67 = (__float_as_uint(p[base + 6]) >> 16) | __float_as_uint(p[base + 7]);
            u32 x01 = __shfl_xor(pk01, 32, 64);
            u32 x23 = __shfl_xor(pk23, 32, 64);
            u32 x45 = __shfl_xor(pk45, 32, 64);
            u32 x67 = __shfl_xor(pk67, 32, 64);
            u32 s01 = lh ? x45 : pk01;
            u32 s23 = lh ? x67 : pk23;
            u32 s45 = lh ? pk45 : x01;
            u32 s67 = lh ? pk67 : x23;
            u32x4 pw = {s01, s23, s45, s67};
            bf16x8 pa = __builtin_bit_cast(bf16x8, pw);
            bf16x8 v0 = *reinterpret_cast<const bf16x8*>(&VSp[lidx(l31,      kh * 32 + ks * 16 + lh * 8)]);
            bf16x8 v1 = *reinterpret_cast<const bf16x8*>(&VSp[lidx(32 + l31, kh * 32 + ks * 16 + lh * 8)]);
            o0 = MFMA32(pa, v0, o0);
            o1 = MFMA32(pa, v1, o1);
        }
    }

    // ---- merge: lrow across (lane-half, wave key-half); O across key-halves ----
    SC[w][l] = lrow;
    __syncthreads();
    float* OSC = (float*)SMEM;                    // [64 q][64 d]
    if (kh == 0) {
        float s = SC[qh][l31] + SC[qh][l31 + 32] + SC[qh + 2][l31] + SC[qh + 2][l31 + 32];
        if (l < 32) ILS[qh * 32 + l31] = 1.0f / s;
    } else {
        #pragma unroll
        for (int r = 0; r < 16; ++r) {
            int q = qh * 32 + (r & 3) + 8 * (r >> 2) + 4 * lh;
            OSC[q * 64 + l31]      = o0[r];
            OSC[q * 64 + 32 + l31] = o1[r];
        }
    }
    __syncthreads();
    if (kh == 0) {
        #pragma unroll
        for (int r = 0; r < 16; ++r) {
            int q = qh * 32 + (r & 3) + 8 * (r >> 2) + 4 * lh;
            float il = ILS[q];
            float v0 = (o0[r] + OSC[q * 64 + l31]) * il;
            float v1 = (o1[r] + OSC[q * 64 + 32 + l31]) * il;
            size_t row = (size_t)b * 2048 + q0 + q;
            size_t off0 = row * 512 + h * 64 + l31;
            u16 h0v = f2bf(v0);
            AOh[off0] = h0v;
            AOl[off0] = f2bf(v0 - bf2f(h0v));
            u16 h1v = f2bf(v1);
            AOh[off0 + 32] = h1v;
            AOl[off0 + 32] = f2bf(v1 - bf2f(h1v));
        }
    }
}

// ---------------------------------------------------------------------------
extern "C" void kernel_launch(void* const* d_in, const int* in_sizes, int n_in,
                              void* d_out, int out_size, void* d_ws, size_t ws_size,
                              hipStream_t stream)
{
    (void)in_sizes; (void)n_in; (void)out_size; (void)ws_size;
    const float* x  = (const float*)d_in[0];
    const float* Wq = (const float*)d_in[1];
    const float* bq = (const float*)d_in[2];
    const float* Wk = (const float*)d_in[3];
    const float* bk = (const float*)d_in[4];
    const float* Wv = (const float*)d_in[5];
    const float* bv = (const float*)d_in[6];
    const float* Wo = (const float*)d_in[7];
    const float* bo = (const float*)d_in[8];
    float* out = (float*)d_out;

    // workspace (54 MB; 67 MB proven available in round 1):
    u16* Xh = (u16*)d_ws;                 // 8 MB (reused as AOh)
    u16* Xl = Xh + 4194304;               // 8 MB (reused as AOl)
    u16* WH = Xl + 4194304;               // 2 MB
    u16* WL = WH + 1048576;               // 2 MB
    u16* Qh = WL + 1048576;               // 8 MB
    u16* Ql = Qh + 4194304;               // 8 MB
    u16* Kh = Ql + 4194304;               // 8 MB
    u16* Vt = Kh + 4194304;               // 8 MB
    u32* MW = (u32*)(Vt + 4194304);       // 2 MB (4-bit mask distances)

    presplit<<<2048, TPB, 0, stream>>>(x, Xh, Xl, 1.0f);
    presplit_w<<<dim3(128, 4), TPB, 0, stream>>>(Wq, Wk, Wv, Wo, WH, WL);
    mask_pre<<<1024, TPB, 0, stream>>>(MW);

    dim3 gg(64, 4);
    gemm_pre<<<gg, TPB, 0, stream>>>(Xh, Xl, WH,          WL,          bq, QSCALE, nullptr, Qh, Ql, 1);
    gemm_pre<<<gg, TPB, 0, stream>>>(Xh, Xl, WH + 262144, WL + 262144, bk, 1.0f,   nullptr, Kh, nullptr, 2);
    gemm_pre<<<gg, TPB, 0, stream>>>(Xh, Xl, WH + 524288, WL + 524288, bv, 1.0f,   nullptr, Vt, nullptr, 3);

    attn32<<<1024, TPB, 0, stream>>>(Qh, Ql, Kh, Vt, MW, Xh, Xl);

    gemm_pre<<<gg, TPB, 0, stream>>>(Xh, Xl, WH + 786432, WL + 786432, bo, 1.0f, out, nullptr, nullptr, 0);
}